// Round 1
// baseline (458.176 us; speedup 1.0000x reference)
//
#include <hip/hip_runtime.h>

#define HH 16
#define DD 64
#define BBATCH 4
#define NSEQ 2048
#define CDIM 1024
#define EPSLN 1e-6f

typedef __bf16 bf16x4 __attribute__((ext_vector_type(4)));
typedef __bf16 bf16x8 __attribute__((ext_vector_type(8)));
typedef float f32x4 __attribute__((ext_vector_type(4)));
typedef short s16x4 __attribute__((ext_vector_type(4)));
typedef short s16x8 __attribute__((ext_vector_type(8)));
typedef unsigned short u16;

__device__ inline u16 f2b(float f) {
  unsigned u = __builtin_bit_cast(unsigned, f);
  u += 0x7fffu + ((u >> 16) & 1u);
  return (u16)(u >> 16);
}
__device__ inline float b2f(u16 s) {
  unsigned u = ((unsigned)s) << 16;
  return __builtin_bit_cast(float, u);
}
// load 8 contiguous bf16 (8B-aligned) as MFMA fragment
__device__ inline bf16x8 ld_frag(const u16* p) {
  s16x4 lo = *(const s16x4*)p;
  s16x4 hi = *(const s16x4*)(p + 4);
  s16x8 v = __builtin_shufflevector(lo, hi, 0, 1, 2, 3, 4, 5, 6, 7);
  return __builtin_bit_cast(bf16x8, v);
}
__device__ inline f32x4 mfma16(bf16x8 a, bf16x8 b, f32x4 c) {
  return __builtin_amdgcn_mfma_f32_16x16x32_bf16(a, b, c, 0, 0, 0);
}

// ---------------- convert x -> bf16 ----------------
__global__ void cvt_x(const float* __restrict__ x, u16* __restrict__ xb) {
  long i = ((long)blockIdx.x * 256 + threadIdx.x) * 8;
  float4 a = *(const float4*)(x + i);
  float4 b = *(const float4*)(x + i + 4);
  u16 r[8];
  r[0] = f2b(a.x); r[1] = f2b(a.y); r[2] = f2b(a.z); r[3] = f2b(a.w);
  r[4] = f2b(b.x); r[5] = f2b(b.y); r[6] = f2b(b.z); r[7] = f2b(b.w);
  *(s16x8*)(xb + i) = *(s16x8*)r;
}

// ---------------- transpose + convert weight: w [K][N] f32 -> wT [N][K] bf16 ----------------
__global__ void cvt_wT(const float* __restrict__ w, u16* __restrict__ wT, int K, int N) {
  __shared__ float tile[32][33];
  int nt = N / 32;
  int bn = blockIdx.x % nt, bk = blockIdx.x / nt;
  int tx = threadIdx.x % 32, ty = threadIdx.x / 32;  // ty 0..7
  int k0 = bk * 32, n0 = bn * 32;
  for (int j = 0; j < 4; j++)
    tile[ty + 8 * j][tx] = w[(long)(k0 + ty + 8 * j) * N + n0 + tx];
  __syncthreads();
  for (int j = 0; j < 4; j++)
    wT[(long)(n0 + ty + 8 * j) * K + k0 + tx] = f2b(tile[tx][ty + 8 * j]);
}

// ---------------- GEMM1: qkv = x @ w_qkv + b, scatter to q/k/v [B,H,N,D] bf16 ----------------
__launch_bounds__(256, 2)
__global__ void gemm_qkv(const u16* __restrict__ A, const u16* __restrict__ BT,
                         const float* __restrict__ bias,
                         u16* __restrict__ qb, u16* __restrict__ kb, u16* __restrict__ vb) {
  const int Kd = CDIM;
  __shared__ u16 As[128 * 68];
  __shared__ u16 Bs[128 * 68];
  int t = threadIdx.x;
  int lane = t & 63, wave = t >> 6;
  int ln = lane & 15, quad = lane >> 4;
  int bm = blockIdx.x % 64, bn = blockIdx.x / 64;
  int wm = (wave >> 1) * 64, wn = (wave & 1) * 64;
  f32x4 acc[4][4] = {};
  for (int kt = 0; kt < Kd / 64; kt++) {
    __syncthreads();
    for (int c = 0; c < 8; c++) {
      int gid = t + 256 * c;
      int row = gid >> 3, c8 = gid & 7;
      const u16* src;
      u16* dst;
      if (row < 128) {
        src = A + ((long)(bm * 128 + row) * Kd + kt * 64 + c8 * 8);
        dst = As + row * 68 + c8 * 8;
      } else {
        int r2 = row - 128;
        src = BT + ((long)(bn * 128 + r2) * Kd + kt * 64 + c8 * 8);
        dst = Bs + r2 * 68 + c8 * 8;
      }
      s16x4 lo = *(const s16x4*)src;
      s16x4 hi = *(const s16x4*)(src + 4);
      *(s16x4*)dst = lo;
      *(s16x4*)(dst + 4) = hi;
    }
    __syncthreads();
    for (int kk = 0; kk < 2; kk++) {
      bf16x8 af[4], bfv[4];
      for (int mt = 0; mt < 4; mt++)
        af[mt] = ld_frag(As + (wm + mt * 16 + ln) * 68 + kk * 32 + quad * 8);
      for (int nt = 0; nt < 4; nt++)
        bfv[nt] = ld_frag(Bs + (wn + nt * 16 + ln) * 68 + kk * 32 + quad * 8);
      for (int mt = 0; mt < 4; mt++)
        for (int nt = 0; nt < 4; nt++)
          acc[mt][nt] = mfma16(af[mt], bfv[nt], acc[mt][nt]);
    }
  }
  // epilogue: scatter with bias. col -> (tensor, head, d)
  for (int mt = 0; mt < 4; mt++)
    for (int nt = 0; nt < 4; nt++) {
      int col = bn * 128 + wn + nt * 16 + ln;
      int tq = col >> 10;
      int rem = col & 1023;
      int h = rem >> 6, d = rem & 63;
      u16* dstbuf = (tq == 0) ? qb : ((tq == 1) ? kb : vb);
      float bv = bias[col];
      for (int r = 0; r < 4; r++) {
        int m = bm * 128 + wm + mt * 16 + quad * 4 + r;
        int b = m >> 11, n = m & 2047;
        dstbuf[((long)((b * HH + h) * NSEQ + n)) * DD + d] = f2b(acc[mt][nt][r] + bv);
      }
    }
}

// ---------------- per-head LayerNorm in place on q,k (q also * D^-0.5) ----------------
__global__ void ln_qk(u16* __restrict__ qb, u16* __restrict__ kb,
                      const float* __restrict__ gq, const float* __restrict__ gk) {
  int lane = threadIdx.x & 63, wave = threadIdx.x >> 6;
  const int nrow = BBATCH * HH * NSEQ;  // 131072 per tensor
  for (int rid = blockIdx.x * 4 + wave; rid < 2 * nrow; rid += gridDim.x * 4) {
    u16* buf = (rid < nrow) ? qb : kb;
    const float* g = (rid < nrow) ? gq : gk;
    float extra = (rid < nrow) ? 0.125f : 1.0f;  // fold softmax scale D^-0.5 into q
    int r = (rid < nrow) ? rid : rid - nrow;
    u16* p = buf + (long)r * 64 + lane;
    float v = b2f(*p);
    float s = v;
    for (int m = 1; m < 64; m <<= 1) s += __shfl_xor(s, m);
    float mu = s * (1.0f / 64.0f);
    float dlt = v - mu;
    float sq = dlt * dlt;
    for (int m = 1; m < 64; m <<= 1) sq += __shfl_xor(sq, m);
    float rstd = rsqrtf(sq * (1.0f / 64.0f) + EPSLN);
    *p = f2b(dlt * rstd * g[lane] * extra);
  }
}

// ---------------- flash attention: o = softmax(q k^T) v, write [B,N,H,D] bf16 ----------------
__launch_bounds__(256, 2)
__global__ void attn(const u16* __restrict__ qb, const u16* __restrict__ kb,
                     const u16* __restrict__ vb, u16* __restrict__ ob) {
  __shared__ u16 Kl[128 * 68];
  __shared__ u16 Vt[64 * 132];
  __shared__ u16 Pl[4 * 16 * 132];
  int t = threadIdx.x, lane = t & 63, wave = t >> 6;
  int ln = lane & 15, quad = lane >> 4;
  int bh = blockIdx.x >> 5;  // 32 q-blocks per (b,h)
  int qblk = blockIdx.x & 31;
  int b = bh >> 4, h = bh & 15;
  const u16* qg = qb + (long)bh * NSEQ * DD;
  const u16* kg = kb + (long)bh * NSEQ * DD;
  const u16* vg = vb + (long)bh * NSEQ * DD;
  int qrow0 = qblk * 64 + wave * 16;
  bf16x8 aq[2];
  for (int kk = 0; kk < 2; kk++)
    aq[kk] = ld_frag(qg + (long)(qrow0 + ln) * DD + kk * 32 + quad * 8);
  f32x4 o[4] = {};
  float mrow[4], lrow[4];
  for (int r = 0; r < 4; r++) { mrow[r] = -1e30f; lrow[r] = 0.f; }
  u16* Pw = Pl + wave * 16 * 132;
  for (int kv = 0; kv < NSEQ / 128; kv++) {
    __syncthreads();
    // stage K tile [128][64] -> stride 68
    for (int c = 0; c < 4; c++) {
      int gid = t + 256 * c;
      int row = gid >> 3, c8 = gid & 7;
      const u16* src = kg + (long)(kv * 128 + row) * DD + c8 * 8;
      u16* dst = Kl + row * 68 + c8 * 8;
      *(s16x4*)dst = *(const s16x4*)src;
      *(s16x4*)(dst + 4) = *(const s16x4*)(src + 4);
    }
    // stage V transposed: Vt[d][k], stride 132
    for (int it = 0; it < 2; it++) {
      int i = t + 256 * it;
      int c = i & 7, rp = i >> 3;
      int db = c * 8, k0 = rp * 2;
      const u16* s0 = vg + (long)(kv * 128 + k0) * DD + db;
      const u16* s1 = s0 + DD;
      u16 lo[8], hi[8];
      *(s16x4*)lo = *(const s16x4*)s0;
      *(s16x4*)(lo + 4) = *(const s16x4*)(s0 + 4);
      *(s16x4*)hi = *(const s16x4*)s1;
      *(s16x4*)(hi + 4) = *(const s16x4*)(s1 + 4);
      for (int j = 0; j < 8; j++) {
        unsigned pk = (unsigned)lo[j] | ((unsigned)hi[j] << 16);
        *(unsigned*)(Vt + (db + j) * 132 + k0) = pk;
      }
    }
    __syncthreads();
    // S = q k^T  (scale already folded into q)
    f32x4 s[8];
    for (int ct = 0; ct < 8; ct++) {
      f32x4 z = {};
      for (int kk = 0; kk < 2; kk++) {
        bf16x8 bk = ld_frag(Kl + (ct * 16 + ln) * 68 + kk * 32 + quad * 8);
        z = mfma16(aq[kk], bk, z);
      }
      s[ct] = z;
    }
    // online softmax (per-row state lives replicated across the 16 lanes of a quad)
    float mnew[4], alpha[4];
    for (int r = 0; r < 4; r++) {
      float vmax = s[0][r];
      for (int ct = 1; ct < 8; ct++) vmax = fmaxf(vmax, s[ct][r]);
      for (int m = 1; m < 16; m <<= 1) vmax = fmaxf(vmax, __shfl_xor(vmax, m));
      mnew[r] = fmaxf(mrow[r], vmax);
      alpha[r] = __expf(mrow[r] - mnew[r]);
      mrow[r] = mnew[r];
    }
    float rsum[4] = {0.f, 0.f, 0.f, 0.f};
    for (int ct = 0; ct < 8; ct++)
      for (int r = 0; r < 4; r++) {
        float p = __expf(s[ct][r] - mnew[r]);
        s[ct][r] = p;
        rsum[r] += p;
      }
    for (int r = 0; r < 4; r++) {
      for (int m = 1; m < 16; m <<= 1) rsum[r] += __shfl_xor(rsum[r], m);
      lrow[r] = lrow[r] * alpha[r] + rsum[r];
      for (int dt = 0; dt < 4; dt++) o[dt][r] *= alpha[r];
    }
    // P (C-layout) -> LDS row-major for A-operand relayout
    for (int ct = 0; ct < 8; ct++)
      for (int r = 0; r < 4; r++)
        Pw[(quad * 4 + r) * 132 + ct * 16 + ln] = f2b(s[ct][r]);
    __syncthreads();
    // O += P V
    bf16x8 ap[4];
    for (int kt = 0; kt < 4; kt++)
      ap[kt] = ld_frag(Pw + ln * 132 + kt * 32 + quad * 8);
    for (int dt = 0; dt < 4; dt++)
      for (int kt = 0; kt < 4; kt++) {
        bf16x8 bv = ld_frag(Vt + (dt * 16 + ln) * 132 + kt * 32 + quad * 8);
        o[dt] = mfma16(ap[kt], bv, o[dt]);
      }
  }
  // epilogue: divide by l, store [B,N,H,D]
  for (int r = 0; r < 4; r++) {
    float inv = 1.0f / lrow[r];
    int n = qrow0 + quad * 4 + r;
    for (int dt = 0; dt < 4; dt++) {
      int d = dt * 16 + ln;
      ob[((long)(b * NSEQ + n) * HH + h) * DD + d] = f2b(o[dt][r] * inv);
    }
  }
}

// ---------------- GEMM2: out = o @ w_proj + b_proj (fp32 out) ----------------
__launch_bounds__(256, 2)
__global__ void gemm_proj(const u16* __restrict__ A, const u16* __restrict__ BT,
                          const float* __restrict__ bias, float* __restrict__ out) {
  const int Kd = CDIM;
  __shared__ u16 As[128 * 68];
  __shared__ u16 Bs[128 * 68];
  int t = threadIdx.x;
  int lane = t & 63, wave = t >> 6;
  int ln = lane & 15, quad = lane >> 4;
  int bm = blockIdx.x % 64, bn = blockIdx.x / 64;
  int wm = (wave >> 1) * 64, wn = (wave & 1) * 64;
  f32x4 acc[4][4] = {};
  for (int kt = 0; kt < Kd / 64; kt++) {
    __syncthreads();
    for (int c = 0; c < 8; c++) {
      int gid = t + 256 * c;
      int row = gid >> 3, c8 = gid & 7;
      const u16* src;
      u16* dst;
      if (row < 128) {
        src = A + ((long)(bm * 128 + row) * Kd + kt * 64 + c8 * 8);
        dst = As + row * 68 + c8 * 8;
      } else {
        int r2 = row - 128;
        src = BT + ((long)(bn * 128 + r2) * Kd + kt * 64 + c8 * 8);
        dst = Bs + r2 * 68 + c8 * 8;
      }
      s16x4 lo = *(const s16x4*)src;
      s16x4 hi = *(const s16x4*)(src + 4);
      *(s16x4*)dst = lo;
      *(s16x4*)(dst + 4) = hi;
    }
    __syncthreads();
    for (int kk = 0; kk < 2; kk++) {
      bf16x8 af[4], bfv[4];
      for (int mt = 0; mt < 4; mt++)
        af[mt] = ld_frag(As + (wm + mt * 16 + ln) * 68 + kk * 32 + quad * 8);
      for (int nt = 0; nt < 4; nt++)
        bfv[nt] = ld_frag(Bs + (wn + nt * 16 + ln) * 68 + kk * 32 + quad * 8);
      for (int mt = 0; mt < 4; mt++)
        for (int nt = 0; nt < 4; nt++)
          acc[mt][nt] = mfma16(af[mt], bfv[nt], acc[mt][nt]);
    }
  }
  for (int mt = 0; mt < 4; mt++)
    for (int nt = 0; nt < 4; nt++) {
      int col = bn * 128 + wn + nt * 16 + ln;
      float bv = bias[col];
      for (int r = 0; r < 4; r++) {
        int m = bm * 128 + wm + mt * 16 + quad * 4 + r;
        out[(long)m * CDIM + col] = acc[mt][nt][r] + bv;
      }
    }
}

extern "C" void kernel_launch(void* const* d_in, const int* in_sizes, int n_in,
                              void* d_out, int out_size, void* d_ws, size_t ws_size,
                              hipStream_t stream) {
  const float* x = (const float*)d_in[0];
  const float* w_qkv = (const float*)d_in[1];
  const float* b_qkv = (const float*)d_in[2];
  // d_in[3]=g_q, d_in[4]=g_k
  const float* g_q = (const float*)d_in[3];
  const float* g_k = (const float*)d_in[4];
  const float* w_proj = (const float*)d_in[5];
  const float* b_proj = (const float*)d_in[6];
  float* out = (float*)d_out;

  char* ws = (char*)d_ws;
  const size_t MB = 1024 * 1024;
  u16* xb = (u16*)ws;                     // 16 MB (x bf16) -- reused as o buffer later
  u16* wqkvT = (u16*)(ws + 16 * MB);      // 6 MB
  u16* wprojT = (u16*)(ws + 22 * MB);     // 2 MB
  u16* qb = (u16*)(ws + 24 * MB);         // 16 MB
  u16* kb = (u16*)(ws + 40 * MB);         // 16 MB
  u16* vb = (u16*)(ws + 56 * MB);         // 16 MB  -> total 72 MB
  u16* ob = xb;                           // alias: x_bf16 dead after gemm_qkv

  cvt_x<<<4096, 256, 0, stream>>>(x, xb);
  cvt_wT<<<(1024 / 32) * (3072 / 32), 256, 0, stream>>>(w_qkv, wqkvT, CDIM, 3 * CDIM);
  cvt_wT<<<(1024 / 32) * (1024 / 32), 256, 0, stream>>>(w_proj, wprojT, CDIM, CDIM);
  gemm_qkv<<<64 * 24, 256, 0, stream>>>(xb, wqkvT, b_qkv, qb, kb, vb);
  ln_qk<<<4096, 256, 0, stream>>>(qb, kb, g_q, g_k);
  attn<<<64 * 32, 256, 0, stream>>>(qb, kb, vb, ob);
  gemm_proj<<<64 * 8, 256, 0, stream>>>(ob, wprojT, b_proj, out);
}